// Round 1
// baseline (682.208 us; speedup 1.0000x reference)
//
#include <hip/hip_runtime.h>
#include <hip/hip_bf16.h>
#include <stdint.h>

#define E_ 2048
#define HQ_ 32
#define HKV_ 8
#define HD_ 64
#define B_ 2
#define T_ 2048
#define MROWS (B_*T_)          // 4096
#define NKV (HKV_*HD_)         // 512
#define NQKV (E_ + 2*NKV)      // 3072
#define SCALE_LOG2E 0.18033688011112042f  // (1/sqrt(64)) * log2(e)

typedef __bf16 bf16_t;
typedef __bf16 bf16x8 __attribute__((ext_vector_type(8)));
typedef float f32x4 __attribute__((ext_vector_type(4)));

typedef const __attribute__((address_space(1))) unsigned int glb_u32;
typedef __attribute__((address_space(3))) unsigned int lds_u32;

__device__ __forceinline__ unsigned short f2bf_bits(float f) {
  unsigned int u = __float_as_uint(f);
  u += 0x7FFFu + ((u >> 16) & 1u);          // RNE
  return (unsigned short)(u >> 16);
}
__device__ __forceinline__ bf16_t f2bf(float f) {
  union { unsigned short s; bf16_t h; } u;
  u.s = f2bf_bits(f);
  return u.h;
}

// ---------------- cast x: f32 -> bf16, 8 elems/thread ----------------
__global__ void cast_x_kernel(const float* __restrict__ in, bf16_t* __restrict__ out, int n8) {
  int i = blockIdx.x * blockDim.x + threadIdx.x;
  int stride = gridDim.x * blockDim.x;
  for (; i < n8; i += stride) {
    const float4* p = reinterpret_cast<const float4*>(in) + (size_t)i * 2;
    float4 a = p[0], b = p[1];
    union { unsigned short s[8]; uint4 v; } u;
    u.s[0] = f2bf_bits(a.x); u.s[1] = f2bf_bits(a.y);
    u.s[2] = f2bf_bits(a.z); u.s[3] = f2bf_bits(a.w);
    u.s[4] = f2bf_bits(b.x); u.s[5] = f2bf_bits(b.y);
    u.s[6] = f2bf_bits(b.z); u.s[7] = f2bf_bits(b.w);
    reinterpret_cast<uint4*>(out)[i] = u.v;
  }
}

// ---------------- W [R][C] f32 -> WT [C][R] bf16 ----------------
// grid (C/32, R/32), block (32,8)
__global__ void transpose_cast_w(const float* __restrict__ in, bf16_t* __restrict__ out,
                                 int R, int C) {
  __shared__ float tile[32][33];
  int c0 = blockIdx.x * 32, r0 = blockIdx.y * 32;
  int tx = threadIdx.x, ty = threadIdx.y;
#pragma unroll
  for (int j = 0; j < 4; ++j) {
    int r = ty + j * 8;
    tile[r][tx] = in[(size_t)(r0 + r) * C + c0 + tx];
  }
  __syncthreads();
#pragma unroll
  for (int j = 0; j < 4; ++j) {
    int c = ty + j * 8;
    out[(size_t)(c0 + c) * R + r0 + tx] = f2bf(tile[tx][c]);
  }
}

// ---------------- V section of QKV -> Vt[b][h][d][t] (bf16 transpose) ----------------
// grid (NKV/32, T/32, B), block (32,8)
__global__ void transpose_v_kernel(const bf16_t* __restrict__ qkv, bf16_t* __restrict__ vt) {
  __shared__ bf16_t tile[32][33];
  int b = blockIdx.z;
  int hd0 = blockIdx.x * 32, t0 = blockIdx.y * 32;
  int tx = threadIdx.x, ty = threadIdx.y;
#pragma unroll
  for (int j = 0; j < 4; ++j) {
    int tt = ty + j * 8;
    tile[tt][tx] = qkv[(size_t)(b * T_ + t0 + tt) * NQKV + (E_ + NKV) + hd0 + tx];
  }
  __syncthreads();
#pragma unroll
  for (int j = 0; j < 4; ++j) {
    int hh = ty + j * 8;
    vt[(size_t)(b * NKV + hd0 + hh) * T_ + t0 + tx] = tile[tx][hh];
  }
}

// ---------------- GEMM: C[M,N] = A[M,K](bf16) * BT[N,K](bf16)^T ----------------
// m97 structure: 128x128 tile, BK=32, 256 thr (4 waves, 2x2 of 64x64),
// global_load_lds width-16 staging, 16x16x32 bf16 MFMA.
// OUTMODE 0: bf16 out.  OUTMODE 1: f32 out + bias[n].
template <int OUTMODE>
__global__ void gemm_bt_kernel(const bf16_t* __restrict__ A, const bf16_t* __restrict__ BT,
                               void* __restrict__ Cv, const float* __restrict__ bias,
                               int M, int N, int K) {
  __shared__ bf16_t As[128 * 32];
  __shared__ bf16_t Bs[128 * 32];
  int tid = threadIdx.x;
  int w = tid >> 6, lane = tid & 63;
  int l15 = lane & 15, l4 = lane >> 4;
  int m0 = blockIdx.x * 128, n0 = blockIdx.y * 128;
  int wm = (w >> 1) * 64, wn = (w & 1) * 64;

  f32x4 zero = {0.f, 0.f, 0.f, 0.f};
  f32x4 acc[4][4];
#pragma unroll
  for (int mt = 0; mt < 4; ++mt)
#pragma unroll
    for (int nt = 0; nt < 4; ++nt) acc[mt][nt] = zero;

  int nK = K >> 5;
  for (int kt = 0; kt < nK; ++kt) {
    int k0 = kt << 5;
    // stage: each wave covers chunks c = w*2 + j; lane i supplies 8 bf16 (16B)
#pragma unroll
    for (int j = 0; j < 2; ++j) {
      int c = w * 2 + j;
      int L = c * 512 + lane * 8;      // linear bf16 index in [128][32] tile
      int row = L >> 5, col = L & 31;
      __builtin_amdgcn_global_load_lds((glb_u32*)(A + (size_t)(m0 + row) * K + k0 + col),
                                       (lds_u32*)(As + c * 512), 16, 0, 0);
      __builtin_amdgcn_global_load_lds((glb_u32*)(BT + (size_t)(n0 + row) * K + k0 + col),
                                       (lds_u32*)(Bs + c * 512), 16, 0, 0);
    }
    __syncthreads();   // compiler emits vmcnt(0) drain before s_barrier

    bf16x8 afr[4], bfr[4];
#pragma unroll
    for (int t = 0; t < 4; ++t) {
      afr[t] = *reinterpret_cast<const bf16x8*>(As + (wm + t * 16 + l15) * 32 + l4 * 8);
      bfr[t] = *reinterpret_cast<const bf16x8*>(Bs + (wn + t * 16 + l15) * 32 + l4 * 8);
    }
#pragma unroll
    for (int mt = 0; mt < 4; ++mt)
#pragma unroll
      for (int nt = 0; nt < 4; ++nt)
        acc[mt][nt] = __builtin_amdgcn_mfma_f32_16x16x32_bf16(afr[mt], bfr[nt], acc[mt][nt], 0, 0, 0);
    __syncthreads();
  }

  // epilogue: C/D layout col = lane&15, row = (lane>>4)*4 + r
  if (OUTMODE == 0) {
    bf16_t* C = reinterpret_cast<bf16_t*>(Cv);
#pragma unroll
    for (int mt = 0; mt < 4; ++mt)
#pragma unroll
      for (int nt = 0; nt < 4; ++nt) {
        int n = n0 + wn + nt * 16 + l15;
#pragma unroll
        for (int r = 0; r < 4; ++r) {
          int m = m0 + wm + mt * 16 + l4 * 4 + r;
          C[(size_t)m * N + n] = f2bf(acc[mt][nt][r]);
        }
      }
  } else {
    float* C = reinterpret_cast<float*>(Cv);
#pragma unroll
    for (int mt = 0; mt < 4; ++mt)
#pragma unroll
      for (int nt = 0; nt < 4; ++nt) {
        int n = n0 + wn + nt * 16 + l15;
        float bb = bias[n];
#pragma unroll
        for (int r = 0; r < 4; ++r) {
          int m = m0 + wm + mt * 16 + l4 * 4 + r;
          C[(size_t)m * N + n] = acc[mt][nt][r] + bb;
        }
      }
  }
}

// ---------------- flash attention ----------------
// grid (T/64, B*HQ), 256 thr = 4 waves, wave w owns q rows [q0+w*16, +16), KV tile = 64.
__global__ void attn_kernel(const bf16_t* __restrict__ qkv, const bf16_t* __restrict__ vt,
                            bf16_t* __restrict__ attn) {
  __shared__ bf16_t P_lds[4 * 16 * 72];   // per-wave 16 x 64, stride 72 (16B aligned, pad)
  int tid = threadIdx.x;
  int w = tid >> 6, lane = tid & 63;
  int l15 = lane & 15, l4 = lane >> 4;
  int bh = blockIdx.y;
  int b = bh >> 5, hq = bh & 31, hkv = hq >> 2;
  int q0 = blockIdx.x * 64 + w * 16;

  // Q fragments: a-frag row = lane&15, k = (lane>>4)*8 (+32 for second chunk)
  const bf16_t* qp = qkv + (size_t)(b * T_ + q0 + l15) * NQKV + hq * HD_ + l4 * 8;
  bf16x8 qf0 = *reinterpret_cast<const bf16x8*>(qp);
  bf16x8 qf1 = *reinterpret_cast<const bf16x8*>(qp + 32);

  f32x4 zero = {0.f, 0.f, 0.f, 0.f};
  f32x4 o[4];
  float m_i[4], l_i[4];
#pragma unroll
  for (int dt = 0; dt < 4; ++dt) o[dt] = zero;
#pragma unroll
  for (int r = 0; r < 4; ++r) { m_i[r] = -1e30f; l_i[r] = 0.f; }

  bf16_t* Pw = P_lds + w * 16 * 72;

  for (int kv0 = 0; kv0 < T_; kv0 += 64) {
    // S = Q * K^T  (raw scores; scale folded into exp2)
    f32x4 s[4];
#pragma unroll
    for (int j = 0; j < 4; ++j) {
      int kk = kv0 + j * 16 + l15;                 // b-frag col = lane&15
      const bf16_t* kp = qkv + (size_t)(b * T_ + kk) * NQKV + E_ + hkv * HD_ + l4 * 8;
      bf16x8 kf0 = *reinterpret_cast<const bf16x8*>(kp);
      bf16x8 kf1 = *reinterpret_cast<const bf16x8*>(kp + 32);
      f32x4 z = zero;
      z = __builtin_amdgcn_mfma_f32_16x16x32_bf16(qf0, kf0, z, 0, 0, 0);
      z = __builtin_amdgcn_mfma_f32_16x16x32_bf16(qf1, kf1, z, 0, 0, 0);
      s[j] = z;
    }
    // online softmax; D rows = (lane>>4)*4 + r, cols = j*16 + (lane&15)
    float p[4][4];
#pragma unroll
    for (int r = 0; r < 4; ++r) {
      float v = fmaxf(fmaxf(s[0][r], s[1][r]), fmaxf(s[2][r], s[3][r]));
#pragma unroll
      for (int off = 1; off < 16; off <<= 1) v = fmaxf(v, __shfl_xor(v, off));
      float mnew = fmaxf(m_i[r], v);
      float corr = exp2f((m_i[r] - mnew) * SCALE_LOG2E);
      l_i[r] *= corr;
#pragma unroll
      for (int dt = 0; dt < 4; ++dt) o[dt][r] *= corr;
      m_i[r] = mnew;
      float ssum = 0.f;
#pragma unroll
      for (int j = 0; j < 4; ++j) {
        p[j][r] = exp2f((s[j][r] - mnew) * SCALE_LOG2E);
        ssum += p[j][r];
      }
#pragma unroll
      for (int off = 1; off < 16; off <<= 1) ssum += __shfl_xor(ssum, off);
      l_i[r] += ssum;
    }
    // P (D-layout) -> LDS -> A-layout fragments
#pragma unroll
    for (int j = 0; j < 4; ++j)
#pragma unroll
      for (int r = 0; r < 4; ++r)
        Pw[(l4 * 4 + r) * 72 + j * 16 + l15] = f2bf(p[j][r]);
    asm volatile("s_waitcnt lgkmcnt(0)" ::: "memory");  // wave-local fence (LDS in-order/wave)
    bf16x8 pf0 = *reinterpret_cast<const bf16x8*>(Pw + l15 * 72 + l4 * 8);
    bf16x8 pf1 = *reinterpret_cast<const bf16x8*>(Pw + l15 * 72 + l4 * 8 + 32);
    // O += P * V   (V from Vt[b][h][d][t]: b-frag col = d, k along t contiguous)
#pragma unroll
    for (int dt = 0; dt < 4; ++dt) {
      const bf16_t* vp = vt + (size_t)((b * HKV_ + hkv) * HD_ + dt * 16 + l15) * T_ + kv0 + l4 * 8;
      bf16x8 vf0 = *reinterpret_cast<const bf16x8*>(vp);
      bf16x8 vf1 = *reinterpret_cast<const bf16x8*>(vp + 32);
      o[dt] = __builtin_amdgcn_mfma_f32_16x16x32_bf16(pf0, vf0, o[dt], 0, 0, 0);
      o[dt] = __builtin_amdgcn_mfma_f32_16x16x32_bf16(pf1, vf1, o[dt], 0, 0, 0);
    }
  }

  float rl[4];
#pragma unroll
  for (int r = 0; r < 4; ++r) rl[r] = 1.0f / l_i[r];
#pragma unroll
  for (int dt = 0; dt < 4; ++dt)
#pragma unroll
    for (int r = 0; r < 4; ++r)
      attn[(size_t)(b * T_ + q0 + l4 * 4 + r) * E_ + hq * HD_ + dt * 16 + l15] =
          f2bf(o[dt][r] * rl[r]);
}

extern "C" void kernel_launch(void* const* d_in, const int* in_sizes, int n_in,
                              void* d_out, int out_size, void* d_ws, size_t ws_size,
                              hipStream_t stream) {
  const float* x  = (const float*)d_in[0];
  const float* Wq = (const float*)d_in[1];
  const float* Wk = (const float*)d_in[2];
  const float* Wv = (const float*)d_in[3];
  const float* Wo = (const float*)d_in[4];
  const float* bo = (const float*)d_in[5];
  float* out = (float*)d_out;

  bf16_t* xb    = (bf16_t*)d_ws;                         // 4096*2048
  bf16_t* WcatT = xb + (size_t)MROWS * E_;               // 3072*2048  ([Wq^T; Wk^T; Wv^T])
  bf16_t* WoT   = WcatT + (size_t)NQKV * E_;             // 2048*2048
  bf16_t* QKV   = WoT + (size_t)E_ * E_;                 // 4096*3072
  bf16_t* Vt    = QKV + (size_t)MROWS * NQKV;            // 2*512*2048
  bf16_t* Attn  = Vt + (size_t)B_ * NKV * T_;            // 4096*2048
  // total ~84 MB of ws

  dim3 tblk(32, 8);
  cast_x_kernel<<<2048, 256, 0, stream>>>(x, xb, MROWS * E_ / 8);
  transpose_cast_w<<<dim3(E_ / 32, E_ / 32), tblk, 0, stream>>>(Wq, WcatT, E_, E_);
  transpose_cast_w<<<dim3(NKV / 32, E_ / 32), tblk, 0, stream>>>(Wk, WcatT + (size_t)E_ * E_, E_, NKV);
  transpose_cast_w<<<dim3(NKV / 32, E_ / 32), tblk, 0, stream>>>(Wv, WcatT + (size_t)(E_ + NKV) * E_, E_, NKV);
  transpose_cast_w<<<dim3(E_ / 32, E_ / 32), tblk, 0, stream>>>(Wo, WoT, E_, E_);

  gemm_bt_kernel<0><<<dim3(MROWS / 128, NQKV / 128), 256, 0, stream>>>(
      xb, WcatT, (void*)QKV, nullptr, MROWS, NQKV, E_);

  transpose_v_kernel<<<dim3(NKV / 32, T_ / 32, B_), tblk, 0, stream>>>(QKV, Vt);

  attn_kernel<<<dim3(T_ / 64, B_ * HQ_), 256, 0, stream>>>(QKV, Vt, Attn);

  gemm_bt_kernel<1><<<dim3(MROWS / 128, E_ / 128), 256, 0, stream>>>(
      Attn, WoT, (void*)out, bo, MROWS, E_, E_);
}

// Round 2
// 430.792 us; speedup vs baseline: 1.5836x; 1.5836x over previous
//
#include <hip/hip_runtime.h>
#include <hip/hip_bf16.h>
#include <stdint.h>

#define E_ 2048
#define HQ_ 32
#define HKV_ 8
#define HD_ 64
#define B_ 2
#define T_ 2048
#define MROWS (B_*T_)          // 4096
#define NKV (HKV_*HD_)         // 512
#define NQKV (E_ + 2*NKV)      // 3072
#define SCALE_LOG2E 0.18033688011112042f  // (1/sqrt(64)) * log2(e)

typedef __bf16 bf16_t;
typedef __bf16 bf16x8 __attribute__((ext_vector_type(8)));
typedef float f32x4 __attribute__((ext_vector_type(4)));

typedef const __attribute__((address_space(1))) unsigned int glb_u32;
typedef __attribute__((address_space(3))) unsigned int lds_u32;

__device__ __forceinline__ unsigned short f2bf_bits(float f) {
  unsigned int u = __float_as_uint(f);
  u += 0x7FFFu + ((u >> 16) & 1u);          // RNE
  return (unsigned short)(u >> 16);
}
__device__ __forceinline__ bf16_t f2bf(float f) {
  union { unsigned short s; bf16_t h; } u;
  u.s = f2bf_bits(f);
  return u.h;
}

// ---------------- cast x: f32 -> bf16, 8 elems/thread ----------------
__global__ void cast_x_kernel(const float* __restrict__ in, bf16_t* __restrict__ out, int n8) {
  int i = blockIdx.x * blockDim.x + threadIdx.x;
  int stride = gridDim.x * blockDim.x;
  for (; i < n8; i += stride) {
    const float4* p = reinterpret_cast<const float4*>(in) + (size_t)i * 2;
    float4 a = p[0], b = p[1];
    union { unsigned short s[8]; uint4 v; } u;
    u.s[0] = f2bf_bits(a.x); u.s[1] = f2bf_bits(a.y);
    u.s[2] = f2bf_bits(a.z); u.s[3] = f2bf_bits(a.w);
    u.s[4] = f2bf_bits(b.x); u.s[5] = f2bf_bits(b.y);
    u.s[6] = f2bf_bits(b.z); u.s[7] = f2bf_bits(b.w);
    reinterpret_cast<uint4*>(out)[i] = u.v;
  }
}

// ---------------- W [R][C] f32 -> WT [C][R] bf16 ----------------
// grid (C/32, R/32), block (32,8)
__global__ void transpose_cast_w(const float* __restrict__ in, bf16_t* __restrict__ out,
                                 int R, int C) {
  __shared__ float tile[32][33];
  int c0 = blockIdx.x * 32, r0 = blockIdx.y * 32;
  int tx = threadIdx.x, ty = threadIdx.y;
#pragma unroll
  for (int j = 0; j < 4; ++j) {
    int r = ty + j * 8;
    tile[r][tx] = in[(size_t)(r0 + r) * C + c0 + tx];
  }
  __syncthreads();
#pragma unroll
  for (int j = 0; j < 4; ++j) {
    int c = ty + j * 8;
    out[(size_t)(c0 + c) * R + r0 + tx] = f2bf(tile[tx][c]);
  }
}

// ---------------- V section of QKV -> Vt[b][h][d][t] (bf16 transpose) ----------------
// grid (NKV/32, T/32, B), block (32,8)
__global__ void transpose_v_kernel(const bf16_t* __restrict__ qkv, bf16_t* __restrict__ vt) {
  __shared__ bf16_t tile[32][33];
  int b = blockIdx.z;
  int hd0 = blockIdx.x * 32, t0 = blockIdx.y * 32;
  int tx = threadIdx.x, ty = threadIdx.y;
#pragma unroll
  for (int j = 0; j < 4; ++j) {
    int tt = ty + j * 8;
    tile[tt][tx] = qkv[(size_t)(b * T_ + t0 + tt) * NQKV + (E_ + NKV) + hd0 + tx];
  }
  __syncthreads();
#pragma unroll
  for (int j = 0; j < 4; ++j) {
    int hh = ty + j * 8;
    vt[(size_t)(b * NKV + hd0 + hh) * T_ + t0 + tx] = tile[tx][hh];
  }
}

// ---------------- GEMM: C[M,N] = A[M,K](bf16) * BT[N,K](bf16)^T ----------------
// m97 structure: 128x128 tile, BK=32, 256 thr (4 waves, 2x2 of 64x64),
// global_load_lds width-16 staging, 16x16x32 bf16 MFMA.
// OUTMODE 0: bf16 out.  OUTMODE 1: f32 out + bias[n].
template <int OUTMODE>
__global__ void gemm_bt_kernel(const bf16_t* __restrict__ A, const bf16_t* __restrict__ BT,
                               void* __restrict__ Cv, const float* __restrict__ bias,
                               int M, int N, int K) {
  __shared__ bf16_t As[128 * 32];
  __shared__ bf16_t Bs[128 * 32];
  int tid = threadIdx.x;
  int w = tid >> 6, lane = tid & 63;
  int l15 = lane & 15, l4 = lane >> 4;
  int m0 = blockIdx.x * 128, n0 = blockIdx.y * 128;
  int wm = (w >> 1) * 64, wn = (w & 1) * 64;

  f32x4 zero = {0.f, 0.f, 0.f, 0.f};
  f32x4 acc[4][4];
#pragma unroll
  for (int mt = 0; mt < 4; ++mt)
#pragma unroll
    for (int nt = 0; nt < 4; ++nt) acc[mt][nt] = zero;

  int nK = K >> 5;
  for (int kt = 0; kt < nK; ++kt) {
    int k0 = kt << 5;
#pragma unroll
    for (int j = 0; j < 2; ++j) {
      int c = w * 2 + j;
      int L = c * 512 + lane * 8;      // linear bf16 index in [128][32] tile
      int row = L >> 5, col = L & 31;
      __builtin_amdgcn_global_load_lds((glb_u32*)(A + (size_t)(m0 + row) * K + k0 + col),
                                       (lds_u32*)(As + c * 512), 16, 0, 0);
      __builtin_amdgcn_global_load_lds((glb_u32*)(BT + (size_t)(n0 + row) * K + k0 + col),
                                       (lds_u32*)(Bs + c * 512), 16, 0, 0);
    }
    __syncthreads();

    bf16x8 afr[4], bfr[4];
#pragma unroll
    for (int t = 0; t < 4; ++t) {
      afr[t] = *reinterpret_cast<const bf16x8*>(As + (wm + t * 16 + l15) * 32 + l4 * 8);
      bfr[t] = *reinterpret_cast<const bf16x8*>(Bs + (wn + t * 16 + l15) * 32 + l4 * 8);
    }
#pragma unroll
    for (int mt = 0; mt < 4; ++mt)
#pragma unroll
      for (int nt = 0; nt < 4; ++nt)
        acc[mt][nt] = __builtin_amdgcn_mfma_f32_16x16x32_bf16(afr[mt], bfr[nt], acc[mt][nt], 0, 0, 0);
    __syncthreads();
  }

  if (OUTMODE == 0) {
    bf16_t* C = reinterpret_cast<bf16_t*>(Cv);
#pragma unroll
    for (int mt = 0; mt < 4; ++mt)
#pragma unroll
      for (int nt = 0; nt < 4; ++nt) {
        int n = n0 + wn + nt * 16 + l15;
#pragma unroll
        for (int r = 0; r < 4; ++r) {
          int m = m0 + wm + mt * 16 + l4 * 4 + r;
          C[(size_t)m * N + n] = f2bf(acc[mt][nt][r]);
        }
      }
  } else {
    float* C = reinterpret_cast<float*>(Cv);
#pragma unroll
    for (int mt = 0; mt < 4; ++mt)
#pragma unroll
      for (int nt = 0; nt < 4; ++nt) {
        int n = n0 + wn + nt * 16 + l15;
        float bb = bias[n];
#pragma unroll
        for (int r = 0; r < 4; ++r) {
          int m = m0 + wm + mt * 16 + l4 * 4 + r;
          C[(size_t)m * N + n] = acc[mt][nt][r] + bb;
        }
      }
  }
}

// ---------------- flash attention (8 waves, LDS-staged K/V, double-buffered) ----------------
// grid (T/128, B*HQ), 512 thr = 8 waves, wave w owns q rows [q0+w*16, +16), KV tile = 64.
// K/V tiles staged once per block via global_load_lds (linear dest) with
// inverse-swizzled SOURCE chunks; ds_reads apply slot = chunk ^ (row&7)
// (the m214 ((row&7)<<4) byte-XOR swizzle -> 2-way conflicts only, free).
__global__ void attn_kernel(const bf16_t* __restrict__ qkv, const bf16_t* __restrict__ vt,
                            bf16_t* __restrict__ attn) {
  __shared__ bf16_t Kbuf[2][64 * 64];
  __shared__ bf16_t Vbuf[2][64 * 64];
  __shared__ bf16_t P_lds[8 * 16 * 72];   // per-wave 16 x 64, stride 72

  int tid = threadIdx.x;
  int w = tid >> 6, lane = tid & 63;
  int l15 = lane & 15, l4 = lane >> 4;
  int bh = blockIdx.y;
  int b = bh >> 5, hq = bh & 31, hkv = hq >> 2;
  int q0 = blockIdx.x * 128 + w * 16;

  // Q fragments: a-frag row = lane&15, k = (lane>>4)*8 (+32 for second chunk)
  const bf16_t* qp = qkv + (size_t)(b * T_ + q0 + l15) * NQKV + hq * HD_ + l4 * 8;
  bf16x8 qf0 = *reinterpret_cast<const bf16x8*>(qp);
  bf16x8 qf1 = *reinterpret_cast<const bf16x8*>(qp + 32);

  f32x4 zero = {0.f, 0.f, 0.f, 0.f};
  f32x4 o[4];
  float m_i[4], l_i[4];
#pragma unroll
  for (int dt = 0; dt < 4; ++dt) o[dt] = zero;
#pragma unroll
  for (int r = 0; r < 4; ++r) { m_i[r] = -1e30f; l_i[r] = 0.f; }

  bf16_t* Pw = P_lds + w * 16 * 72;

  // staging geometry: wave w stages rows [w*8, w*8+8) of each 64x64 tile.
  // linear LDS dest (uniform base + lane*16B); source chunk inverse-swizzled.
  int srow = w * 8 + (lane >> 3);                 // row within tile this lane feeds
  int schunk = (lane & 7) ^ ((lane >> 3) & 7);    // global 16B-chunk to fetch
  const bf16_t* kg = qkv + (size_t)b * T_ * NQKV + E_ + hkv * HD_;
  const bf16_t* vg = vt + ((size_t)(b * HKV_ + hkv) * HD_ + srow) * T_;

#define STAGE_KV(bi, kv0) do {                                                          \
    __builtin_amdgcn_global_load_lds(                                                   \
        (glb_u32*)(kg + (size_t)((kv0) + srow) * NQKV + schunk * 8),                    \
        (lds_u32*)(&Kbuf[bi][w * 8 * 64]), 16, 0, 0);                                   \
    __builtin_amdgcn_global_load_lds(                                                   \
        (glb_u32*)(vg + (kv0) + schunk * 8),                                            \
        (lds_u32*)(&Vbuf[bi][w * 8 * 64]), 16, 0, 0);                                   \
  } while (0)

  STAGE_KV(0, 0);
  __syncthreads();

#pragma unroll 2
  for (int t = 0; t < T_ / 64; ++t) {
    int bi = t & 1;
    if (t < T_ / 64 - 1) STAGE_KV(bi ^ 1, (t + 1) * 64);

    // ---- S = Q * K^T (K from LDS, swizzled reads)
    f32x4 s[4];
    __builtin_amdgcn_s_setprio(1);
#pragma unroll
    for (int j = 0; j < 4; ++j) {
      int kr = j * 16 + l15;                      // K row within tile (b-frag col)
      const bf16_t* kb = &Kbuf[bi][kr * 64];
      bf16x8 kf0 = *reinterpret_cast<const bf16x8*>(kb + ((l4 ^ (kr & 7)) * 8));
      bf16x8 kf1 = *reinterpret_cast<const bf16x8*>(kb + (((4 + l4) ^ (kr & 7)) * 8));
      f32x4 z = zero;
      z = __builtin_amdgcn_mfma_f32_16x16x32_bf16(qf0, kf0, z, 0, 0, 0);
      z = __builtin_amdgcn_mfma_f32_16x16x32_bf16(qf1, kf1, z, 0, 0, 0);
      s[j] = z;
    }
    __builtin_amdgcn_s_setprio(0);

    // ---- online softmax; D rows = (lane>>4)*4 + r, cols = j*16 + (lane&15)
    float p[4][4];
#pragma unroll
    for (int r = 0; r < 4; ++r) {
      float v = fmaxf(fmaxf(s[0][r], s[1][r]), fmaxf(s[2][r], s[3][r]));
#pragma unroll
      for (int off = 1; off < 16; off <<= 1) v = fmaxf(v, __shfl_xor(v, off));
      float mnew = fmaxf(m_i[r], v);
      float corr = exp2f((m_i[r] - mnew) * SCALE_LOG2E);
      l_i[r] *= corr;
#pragma unroll
      for (int dt = 0; dt < 4; ++dt) o[dt][r] *= corr;
      m_i[r] = mnew;
      float ssum = 0.f;
#pragma unroll
      for (int j = 0; j < 4; ++j) {
        p[j][r] = exp2f((s[j][r] - mnew) * SCALE_LOG2E);
        ssum += p[j][r];
      }
#pragma unroll
      for (int off = 1; off < 16; off <<= 1) ssum += __shfl_xor(ssum, off);
      l_i[r] += ssum;
    }

    // ---- P (D-layout) -> LDS -> A-layout fragments (wave-private region)
#pragma unroll
    for (int j = 0; j < 4; ++j)
#pragma unroll
      for (int r = 0; r < 4; ++r)
        Pw[(l4 * 4 + r) * 72 + j * 16 + l15] = f2bf(p[j][r]);
    asm volatile("s_waitcnt lgkmcnt(0)" ::: "memory");
    bf16x8 pf0 = *reinterpret_cast<const bf16x8*>(Pw + l15 * 72 + l4 * 8);
    bf16x8 pf1 = *reinterpret_cast<const bf16x8*>(Pw + l15 * 72 + l4 * 8 + 32);

    // ---- O += P * V (V from LDS, swizzled reads; b-frag col = d, k along t)
    __builtin_amdgcn_s_setprio(1);
#pragma unroll
    for (int dt = 0; dt < 4; ++dt) {
      int vr = dt * 16 + l15;                     // d row within tile (b-frag col)
      const bf16_t* vb = &Vbuf[bi][vr * 64];
      bf16x8 vf0 = *reinterpret_cast<const bf16x8*>(vb + ((l4 ^ (vr & 7)) * 8));
      bf16x8 vf1 = *reinterpret_cast<const bf16x8*>(vb + (((4 + l4) ^ (vr & 7)) * 8));
      o[dt] = __builtin_amdgcn_mfma_f32_16x16x32_bf16(pf0, vf0, o[dt], 0, 0, 0);
      o[dt] = __builtin_amdgcn_mfma_f32_16x16x32_bf16(pf1, vf1, o[dt], 0, 0, 0);
    }
    __builtin_amdgcn_s_setprio(0);

    __syncthreads();   // buffer bi fully consumed; staged bi^1 drained (vmcnt 0)
  }
#undef STAGE_KV

  float rl[4];
#pragma unroll
  for (int r = 0; r < 4; ++r) rl[r] = 1.0f / l_i[r];
#pragma unroll
  for (int dt = 0; dt < 4; ++dt)
#pragma unroll
    for (int r = 0; r < 4; ++r)
      attn[(size_t)(b * T_ + q0 + l4 * 4 + r) * E_ + hq * HD_ + dt * 16 + l15] =
          f2bf(o[dt][r] * rl[r]);
}

extern "C" void kernel_launch(void* const* d_in, const int* in_sizes, int n_in,
                              void* d_out, int out_size, void* d_ws, size_t ws_size,
                              hipStream_t stream) {
  const float* x  = (const float*)d_in[0];
  const float* Wq = (const float*)d_in[1];
  const float* Wk = (const float*)d_in[2];
  const float* Wv = (const float*)d_in[3];
  const float* Wo = (const float*)d_in[4];
  const float* bo = (const float*)d_in[5];
  float* out = (float*)d_out;

  bf16_t* xb    = (bf16_t*)d_ws;                         // 4096*2048
  bf16_t* WcatT = xb + (size_t)MROWS * E_;               // 3072*2048  ([Wq^T; Wk^T; Wv^T])
  bf16_t* WoT   = WcatT + (size_t)NQKV * E_;             // 2048*2048
  bf16_t* QKV   = WoT + (size_t)E_ * E_;                 // 4096*3072
  bf16_t* Vt    = QKV + (size_t)MROWS * NQKV;            // 2*512*2048
  bf16_t* Attn  = Vt + (size_t)B_ * NKV * T_;            // 4096*2048

  dim3 tblk(32, 8);
  cast_x_kernel<<<2048, 256, 0, stream>>>(x, xb, MROWS * E_ / 8);
  transpose_cast_w<<<dim3(E_ / 32, E_ / 32), tblk, 0, stream>>>(Wq, WcatT, E_, E_);
  transpose_cast_w<<<dim3(NKV / 32, E_ / 32), tblk, 0, stream>>>(Wk, WcatT + (size_t)E_ * E_, E_, NKV);
  transpose_cast_w<<<dim3(NKV / 32, E_ / 32), tblk, 0, stream>>>(Wv, WcatT + (size_t)(E_ + NKV) * E_, E_, NKV);
  transpose_cast_w<<<dim3(E_ / 32, E_ / 32), tblk, 0, stream>>>(Wo, WoT, E_, E_);

  gemm_bt_kernel<0><<<dim3(MROWS / 128, NQKV / 128), 256, 0, stream>>>(
      xb, WcatT, (void*)QKV, nullptr, MROWS, NQKV, E_);

  transpose_v_kernel<<<dim3(NKV / 32, T_ / 32, B_), tblk, 0, stream>>>(QKV, Vt);

  attn_kernel<<<dim3(T_ / 128, B_ * HQ_), 512, 0, stream>>>(QKV, Vt, Attn);

  gemm_bt_kernel<1><<<dim3(MROWS / 128, E_ / 128), 256, 0, stream>>>(
      Attn, WoT, (void*)out, bo, MROWS, E_, E_);
}

// Round 4
// 381.825 us; speedup vs baseline: 1.7867x; 1.1282x over previous
//
#include <hip/hip_runtime.h>
#include <hip/hip_bf16.h>
#include <stdint.h>

#define E_ 2048
#define HQ_ 32
#define HKV_ 8
#define HD_ 64
#define B_ 2
#define T_ 2048
#define MROWS (B_*T_)          // 4096
#define NKV (HKV_*HD_)         // 512
#define NQKV (E_ + 2*NKV)      // 3072
#define SCALE_LOG2E 0.18033688011112042f  // (1/sqrt(64)) * log2(e)

typedef __bf16 bf16_t;
typedef __bf16 bf16x8 __attribute__((ext_vector_type(8)));
typedef float f32x4 __attribute__((ext_vector_type(4)));
typedef float f32x16 __attribute__((ext_vector_type(16)));

typedef const __attribute__((address_space(1))) unsigned int glb_u32;
typedef __attribute__((address_space(3))) unsigned int lds_u32;

__device__ __forceinline__ unsigned short f2bf_bits(float f) {
  unsigned int u = __float_as_uint(f);
  u += 0x7FFFu + ((u >> 16) & 1u);          // RNE
  return (unsigned short)(u >> 16);
}
__device__ __forceinline__ bf16_t f2bf(float f) {
  union { unsigned short s; bf16_t h; } u;
  u.s = f2bf_bits(f);
  return u.h;
}
// paired cast -> compiler emits v_cvt_pk_bf16_f32 (RNE)
__device__ __forceinline__ unsigned pack2bf(float lo, float hi) {
  union { struct { bf16_t l, h; } s; unsigned u; } c;
  c.s.l = (bf16_t)lo; c.s.h = (bf16_t)hi;
  return c.u;
}
__device__ __forceinline__ float fexp2(float x) {
#if __has_builtin(__builtin_amdgcn_exp2f)
  return __builtin_amdgcn_exp2f(x);
#else
  return exp2f(x);
#endif
}

// ---------------- cast x: f32 -> bf16, 8 elems/thread ----------------
__global__ void cast_x_kernel(const float* __restrict__ in, bf16_t* __restrict__ out, int n8) {
  int i = blockIdx.x * blockDim.x + threadIdx.x;
  int stride = gridDim.x * blockDim.x;
  for (; i < n8; i += stride) {
    const float4* p = reinterpret_cast<const float4*>(in) + (size_t)i * 2;
    float4 a = p[0], b = p[1];
    union { unsigned short s[8]; uint4 v; } u;
    u.s[0] = f2bf_bits(a.x); u.s[1] = f2bf_bits(a.y);
    u.s[2] = f2bf_bits(a.z); u.s[3] = f2bf_bits(a.w);
    u.s[4] = f2bf_bits(b.x); u.s[5] = f2bf_bits(b.y);
    u.s[6] = f2bf_bits(b.z); u.s[7] = f2bf_bits(b.w);
    reinterpret_cast<uint4*>(out)[i] = u.v;
  }
}

// ---------------- W [R][C] f32 -> WT [C][R] bf16 ----------------
__global__ void transpose_cast_w(const float* __restrict__ in, bf16_t* __restrict__ out,
                                 int R, int C) {
  __shared__ float tile[32][33];
  int c0 = blockIdx.x * 32, r0 = blockIdx.y * 32;
  int tx = threadIdx.x, ty = threadIdx.y;
#pragma unroll
  for (int j = 0; j < 4; ++j) {
    int r = ty + j * 8;
    tile[r][tx] = in[(size_t)(r0 + r) * C + c0 + tx];
  }
  __syncthreads();
#pragma unroll
  for (int j = 0; j < 4; ++j) {
    int c = ty + j * 8;
    out[(size_t)(c0 + c) * R + r0 + tx] = f2bf(tile[tx][c]);
  }
}

// ---------------- V section of QKV -> Vt[b][h][d][t] ----------------
__global__ void transpose_v_kernel(const bf16_t* __restrict__ qkv, bf16_t* __restrict__ vt) {
  __shared__ bf16_t tile[32][33];
  int b = blockIdx.z;
  int hd0 = blockIdx.x * 32, t0 = blockIdx.y * 32;
  int tx = threadIdx.x, ty = threadIdx.y;
#pragma unroll
  for (int j = 0; j < 4; ++j) {
    int tt = ty + j * 8;
    tile[tt][tx] = qkv[(size_t)(b * T_ + t0 + tt) * NQKV + (E_ + NKV) + hd0 + tx];
  }
  __syncthreads();
#pragma unroll
  for (int j = 0; j < 4; ++j) {
    int hh = ty + j * 8;
    vt[(size_t)(b * NKV + hd0 + hh) * T_ + t0 + tx] = tile[tx][hh];
  }
}

// ---------------- GEMM (m97 structure, unchanged) ----------------
template <int OUTMODE>
__global__ void gemm_bt_kernel(const bf16_t* __restrict__ A, const bf16_t* __restrict__ BT,
                               void* __restrict__ Cv, const float* __restrict__ bias,
                               int M, int N, int K) {
  __shared__ bf16_t As[128 * 32];
  __shared__ bf16_t Bs[128 * 32];
  int tid = threadIdx.x;
  int w = tid >> 6, lane = tid & 63;
  int l15 = lane & 15, l4 = lane >> 4;
  int m0 = blockIdx.x * 128, n0 = blockIdx.y * 128;
  int wm = (w >> 1) * 64, wn = (w & 1) * 64;

  f32x4 zero = {0.f, 0.f, 0.f, 0.f};
  f32x4 acc[4][4];
#pragma unroll
  for (int mt = 0; mt < 4; ++mt)
#pragma unroll
    for (int nt = 0; nt < 4; ++nt) acc[mt][nt] = zero;

  int nK = K >> 5;
  for (int kt = 0; kt < nK; ++kt) {
    int k0 = kt << 5;
#pragma unroll
    for (int j = 0; j < 2; ++j) {
      int c = w * 2 + j;
      int L = c * 512 + lane * 8;
      int row = L >> 5, col = L & 31;
      __builtin_amdgcn_global_load_lds((glb_u32*)(A + (size_t)(m0 + row) * K + k0 + col),
                                       (lds_u32*)(As + c * 512), 16, 0, 0);
      __builtin_amdgcn_global_load_lds((glb_u32*)(BT + (size_t)(n0 + row) * K + k0 + col),
                                       (lds_u32*)(Bs + c * 512), 16, 0, 0);
    }
    __syncthreads();

    bf16x8 afr[4], bfr[4];
#pragma unroll
    for (int t = 0; t < 4; ++t) {
      afr[t] = *reinterpret_cast<const bf16x8*>(As + (wm + t * 16 + l15) * 32 + l4 * 8);
      bfr[t] = *reinterpret_cast<const bf16x8*>(Bs + (wn + t * 16 + l15) * 32 + l4 * 8);
    }
#pragma unroll
    for (int mt = 0; mt < 4; ++mt)
#pragma unroll
      for (int nt = 0; nt < 4; ++nt)
        acc[mt][nt] = __builtin_amdgcn_mfma_f32_16x16x32_bf16(afr[mt], bfr[nt], acc[mt][nt], 0, 0, 0);
    __syncthreads();
  }

  if (OUTMODE == 0) {
    bf16_t* C = reinterpret_cast<bf16_t*>(Cv);
#pragma unroll
    for (int mt = 0; mt < 4; ++mt)
#pragma unroll
      for (int nt = 0; nt < 4; ++nt) {
        int n = n0 + wn + nt * 16 + l15;
#pragma unroll
        for (int r = 0; r < 4; ++r) {
          int m = m0 + wm + mt * 16 + l4 * 4 + r;
          C[(size_t)m * N + n] = f2bf(acc[mt][nt][r]);
        }
      }
  } else {
    float* C = reinterpret_cast<float*>(Cv);
#pragma unroll
    for (int mt = 0; mt < 4; ++mt)
#pragma unroll
      for (int nt = 0; nt < 4; ++nt) {
        int n = n0 + wn + nt * 16 + l15;
        float bb = bias[n];
#pragma unroll
        for (int r = 0; r < 4; ++r) {
          int m = m0 + wm + mt * 16 + l4 * 4 + r;
          C[(size_t)m * N + n] = acc[mt][nt][r] + bb;
        }
      }
  }
}

// ---------------- flash attention: 8 waves x 32 q-rows, 32x32 swapped QK^T ----------------
// grid (T/256, B*HQ), 512 thr. KV tile 64, double-buffered LDS (XOR-swizzled via
// pre-swizzled global source + swizzled reads). Softmax fully in-register:
// S^T = mfma(K, Q) puts q = lane&31 (col), k = crow(r,hi) (row); defer-max (THR=8 log2);
// deferred l-reduce; P A-frags built via paired bf16 casts + shfl_xor(32) half-exchange.
__global__ void attn_kernel(const bf16_t* __restrict__ qkv, const bf16_t* __restrict__ vt,
                            bf16_t* __restrict__ attn) {
  __shared__ bf16_t Kbuf[2][64 * 64];
  __shared__ bf16_t Vbuf[2][64 * 64];
  __shared__ float bcast[8][32];

  int tid = threadIdx.x;
  int w = tid >> 6, lane = tid & 63;
  int l31 = lane & 31, hi = lane >> 5;
  int bh = blockIdx.y;
  int b = bh >> 5, hq = bh & 31, hkv = hq >> 2;
  int q0 = blockIdx.x * 256 + w * 32;

  // Q (B-operand): col q = lane&31, d = s*16 + hi*8 + [0..8); pre-scaled
  bf16x8 qf[4];
  {
    const bf16_t* qp = qkv + (size_t)(b * T_ + q0 + l31) * NQKV + hq * HD_;
#pragma unroll
    for (int s = 0; s < 4; ++s) {
      bf16x8 q = *reinterpret_cast<const bf16x8*>(qp + s * 16 + hi * 8);
#pragma unroll
      for (int e = 0; e < 8; ++e) q[e] = (bf16_t)((float)q[e] * SCALE_LOG2E);
      qf[s] = q;
    }
  }

  f32x16 o0 = {0.f,0.f,0.f,0.f,0.f,0.f,0.f,0.f,0.f,0.f,0.f,0.f,0.f,0.f,0.f,0.f};
  f32x16 o1 = o0;
  float m_r = -1e30f, l_r = 0.f;

  // staging: wave w stages rows [w*8, w*8+8); linear LDS dest, source chunk pre-swizzled
  int srow = w * 8 + (lane >> 3);
  int schunk = (lane & 7) ^ ((lane >> 3) & 7);
  const bf16_t* kg = qkv + (size_t)b * T_ * NQKV + E_ + hkv * HD_;
  const bf16_t* vg = vt + ((size_t)(b * HKV_ + hkv) * HD_ + srow) * T_;

#define STAGE_KV(bi, kv0) do {                                                          \
    __builtin_amdgcn_global_load_lds(                                                   \
        (glb_u32*)(kg + (size_t)((kv0) + srow) * NQKV + schunk * 8),                    \
        (lds_u32*)(&Kbuf[bi][w * 8 * 64]), 16, 0, 0);                                   \
    __builtin_amdgcn_global_load_lds(                                                   \
        (glb_u32*)(vg + (kv0) + schunk * 8),                                            \
        (lds_u32*)(&Vbuf[bi][w * 8 * 64]), 16, 0, 0);                                   \
  } while (0)

  // swizzled reads: slot = (2s+hi) ^ (row&7); row&7 == l31&7 (rows are l31 + 32k)
#define KREAD(bi, tsub, s) \
  (*reinterpret_cast<const bf16x8*>(&Kbuf[bi][((tsub) * 32 + l31) * 64 + \
      ((((s) * 2 + hi) ^ (l31 & 7)) * 8)]))
#define VREAD(bi, dh, s) \
  (*reinterpret_cast<const bf16x8*>(&Vbuf[bi][((dh) * 32 + l31) * 64 + \
      ((((s) * 2 + hi) ^ (l31 & 7)) * 8)]))

  STAGE_KV(0, 0);
  __syncthreads();

#pragma unroll 2
  for (int t = 0; t < T_ / 64; ++t) {
    int bi = t & 1;
    if (t < T_ / 64 - 1) STAGE_KV(bi ^ 1, (t + 1) * 64);

    // ---- S^T = K * Q : lane holds col q=l31; rows k = crow(r,hi) (+32 for sb)
    f32x16 sa = {0.f,0.f,0.f,0.f,0.f,0.f,0.f,0.f,0.f,0.f,0.f,0.f,0.f,0.f,0.f,0.f};
    f32x16 sb = sa;
    __builtin_amdgcn_s_setprio(1);
#pragma unroll
    for (int s = 0; s < 4; ++s) {
      sa = __builtin_amdgcn_mfma_f32_32x32x16_bf16(KREAD(bi, 0, s), qf[s], sa, 0, 0, 0);
      sb = __builtin_amdgcn_mfma_f32_32x32x16_bf16(KREAD(bi, 1, s), qf[s], sb, 0, 0, 0);
    }
    __builtin_amdgcn_s_setprio(0);

    // ---- defer-max online softmax (scores already in log2 units)
    float pmax = sa[0];
#pragma unroll
    for (int r = 1; r < 16; ++r) pmax = fmaxf(pmax, sa[r]);
#pragma unroll
    for (int r = 0; r < 16; ++r) pmax = fmaxf(pmax, sb[r]);

    if (__any(pmax > m_r + 8.f)) {
      float pm2 = __shfl_xor(pmax, 32);
      float mnew = fmaxf(m_r, fmaxf(pmax, pm2));
      float corr = fexp2(m_r - mnew);
      m_r = mnew;
      l_r *= corr;
      bcast[w][l31] = corr;                       // both hi lanes write same value
      asm volatile("s_waitcnt lgkmcnt(0)" ::: "memory");
#pragma unroll
      for (int r = 0; r < 16; ++r) {
        float c = bcast[w][(r & 3) + 8 * (r >> 2) + 4 * hi];
        o0[r] *= c; o1[r] *= c;
      }
    }

    float pA[16], pB[16];
    float ps0 = 0.f, ps1 = 0.f;
#pragma unroll
    for (int r = 0; r < 16; ++r) {
      pA[r] = fexp2(sa[r] - m_r); ps0 += pA[r];
      pB[r] = fexp2(sb[r] - m_r); ps1 += pB[r];
    }
    l_r += ps0 + ps1;                              // partial (own half-row); reduced at end

    // ---- pack P to bf16 words: wd[t][g][j] holds k-pair {8g+4hi+32t+2j, +1}
    unsigned wd[2][4][2];
#pragma unroll
    for (int g = 0; g < 4; ++g)
#pragma unroll
      for (int j = 0; j < 2; ++j) {
        wd[0][g][j] = pack2bf(pA[4 * g + 2 * j], pA[4 * g + 2 * j + 1]);
        wd[1][g][j] = pack2bf(pB[4 * g + 2 * j], pB[4 * g + 2 * j + 1]);
      }

    // ---- O += P * V ; P A-frag per k-step s: lane needs k = 16s + 8*hi + [0..8).
    // Own half supplies 4 of those; the partner lane (lane^32) owns the other 4:
    // lo needs hi's group gg words; hi needs lo's group gg+1 words. Exchange via
    // shfl_xor(32) (semantics-safe replacement for v_permlane32_swap_b32).
    __builtin_amdgcn_s_setprio(1);
#pragma unroll
    for (int s = 0; s < 4; ++s) {
      const int tt = s >> 1, gg = 2 * (s & 1);
      unsigned send0 = hi ? wd[tt][gg][0] : wd[tt][gg + 1][0];
      unsigned send1 = hi ? wd[tt][gg][1] : wd[tt][gg + 1][1];
      unsigned recv0 = __shfl_xor(send0, 32);
      unsigned recv1 = __shfl_xor(send1, 32);
      union { unsigned u[4]; bf16x8 v; } pf;
      pf.u[0] = hi ? recv0 : wd[tt][gg][0];       // k = 16s + {0,1} / {8,9}
      pf.u[1] = hi ? recv1 : wd[tt][gg][1];       // k = 16s + {2,3} / {10,11}
      pf.u[2] = hi ? wd[tt][gg + 1][0] : recv0;   // k = 16s + {4,5} / {12,13}
      pf.u[3] = hi ? wd[tt][gg + 1][1] : recv1;   // k = 16s + {6,7} / {14,15}
      o0 = __builtin_amdgcn_mfma_f32_32x32x16_bf16(pf.v, VREAD(bi, 0, s), o0, 0, 0, 0);
      o1 = __builtin_amdgcn_mfma_f32_32x32x16_bf16(pf.v, VREAD(bi, 1, s), o1, 0, 0, 0);
    }
    __builtin_amdgcn_s_setprio(0);

    __syncthreads();
  }
#undef STAGE_KV
#undef KREAD
#undef VREAD

  // ---- epilogue: full l, broadcast 1/l across the q<->crow lane remap, write
  float lfull = l_r + __shfl_xor(l_r, 32);
  bcast[w][l31] = 1.0f / lfull;
  asm volatile("s_waitcnt lgkmcnt(0)" ::: "memory");
  const size_t obase = (size_t)(b * T_ + q0) * E_ + hq * HD_;
#pragma unroll
  for (int r = 0; r < 16; ++r) {
    int q = (r & 3) + 8 * (r >> 2) + 4 * hi;
    float rl = bcast[w][q];
    attn[obase + (size_t)q * E_ + l31]      = (bf16_t)(o0[r] * rl);
    attn[obase + (size_t)q * E_ + 32 + l31] = (bf16_t)(o1[r] * rl);
  }
}

extern "C" void kernel_launch(void* const* d_in, const int* in_sizes, int n_in,
                              void* d_out, int out_size, void* d_ws, size_t ws_size,
                              hipStream_t stream) {
  const float* x  = (const float*)d_in[0];
  const float* Wq = (const float*)d_in[1];
  const float* Wk = (const float*)d_in[2];
  const float* Wv = (const float*)d_in[3];
  const float* Wo = (const float*)d_in[4];
  const float* bo = (const float*)d_in[5];
  float* out = (float*)d_out;

  bf16_t* xb    = (bf16_t*)d_ws;                         // 4096*2048
  bf16_t* WcatT = xb + (size_t)MROWS * E_;               // 3072*2048
  bf16_t* WoT   = WcatT + (size_t)NQKV * E_;             // 2048*2048
  bf16_t* QKV   = WoT + (size_t)E_ * E_;                 // 4096*3072
  bf16_t* Vt    = QKV + (size_t)MROWS * NQKV;            // 2*512*2048
  bf16_t* Attn  = Vt + (size_t)B_ * NKV * T_;            // 4096*2048

  dim3 tblk(32, 8);
  cast_x_kernel<<<2048, 256, 0, stream>>>(x, xb, MROWS * E_ / 8);
  transpose_cast_w<<<dim3(E_ / 32, E_ / 32), tblk, 0, stream>>>(Wq, WcatT, E_, E_);
  transpose_cast_w<<<dim3(NKV / 32, E_ / 32), tblk, 0, stream>>>(Wk, WcatT + (size_t)E_ * E_, E_, NKV);
  transpose_cast_w<<<dim3(NKV / 32, E_ / 32), tblk, 0, stream>>>(Wv, WcatT + (size_t)(E_ + NKV) * E_, E_, NKV);
  transpose_cast_w<<<dim3(E_ / 32, E_ / 32), tblk, 0, stream>>>(Wo, WoT, E_, E_);

  gemm_bt_kernel<0><<<dim3(MROWS / 128, NQKV / 128), 256, 0, stream>>>(
      xb, WcatT, (void*)QKV, nullptr, MROWS, NQKV, E_);

  transpose_v_kernel<<<dim3(NKV / 32, T_ / 32, B_), tblk, 0, stream>>>(QKV, Vt);

  attn_kernel<<<dim3(T_ / 256, B_ * HQ_), 512, 0, stream>>>(QKV, Vt, Attn);

  gemm_bt_kernel<1><<<dim3(MROWS / 128, E_ / 128), 256, 0, stream>>>(
      Attn, WoT, (void*)out, bo, MROWS, E_, E_);
}

// Round 6
// 375.155 us; speedup vs baseline: 1.8185x; 1.0178x over previous
//
#include <hip/hip_runtime.h>
#include <hip/hip_bf16.h>
#include <stdint.h>

#define E_ 2048
#define HQ_ 32
#define HKV_ 8
#define HD_ 64
#define B_ 2
#define T_ 2048
#define MROWS (B_*T_)          // 4096
#define NKV (HKV_*HD_)         // 512
#define NQKV (E_ + 2*NKV)      // 3072
#define SCALE_LOG2E 0.18033688011112042f  // (1/sqrt(64)) * log2(e)

typedef __bf16 bf16_t;
typedef __bf16 bf16x8 __attribute__((ext_vector_type(8)));
typedef float f32x4 __attribute__((ext_vector_type(4)));
typedef float f32x16 __attribute__((ext_vector_type(16)));

typedef const __attribute__((address_space(1))) unsigned int glb_u32;
typedef __attribute__((address_space(3))) unsigned int lds_u32;

__device__ __forceinline__ unsigned short f2bf_bits(float f) {
  unsigned int u = __float_as_uint(f);
  u += 0x7FFFu + ((u >> 16) & 1u);          // RNE
  return (unsigned short)(u >> 16);
}
__device__ __forceinline__ bf16_t f2bf(float f) {
  union { unsigned short s; bf16_t h; } u;
  u.s = f2bf_bits(f);
  return u.h;
}
__device__ __forceinline__ unsigned pack2bf(float lo, float hi) {
  union { struct { bf16_t l, h; } s; unsigned u; } c;
  c.s.l = (bf16_t)lo; c.s.h = (bf16_t)hi;
  return c.u;
}
__device__ __forceinline__ float fexp2(float x) {
#if __has_builtin(__builtin_amdgcn_exp2f)
  return __builtin_amdgcn_exp2f(x);
#else
  return exp2f(x);
#endif
}

// ---------------- cast x: f32 -> bf16, 8 elems/thread ----------------
__global__ void cast_x_kernel(const float* __restrict__ in, bf16_t* __restrict__ out, int n8) {
  int i = blockIdx.x * blockDim.x + threadIdx.x;
  int stride = gridDim.x * blockDim.x;
  for (; i < n8; i += stride) {
    const float4* p = reinterpret_cast<const float4*>(in) + (size_t)i * 2;
    float4 a = p[0], b = p[1];
    union { unsigned short s[8]; uint4 v; } u;
    u.s[0] = f2bf_bits(a.x); u.s[1] = f2bf_bits(a.y);
    u.s[2] = f2bf_bits(a.z); u.s[3] = f2bf_bits(a.w);
    u.s[4] = f2bf_bits(b.x); u.s[5] = f2bf_bits(b.y);
    u.s[6] = f2bf_bits(b.z); u.s[7] = f2bf_bits(b.w);
    reinterpret_cast<uint4*>(out)[i] = u.v;
  }
}

// ---------------- W [R][C] f32 -> WT [C][R] bf16 ----------------
__global__ void transpose_cast_w(const float* __restrict__ in, bf16_t* __restrict__ out,
                                 int R, int C) {
  __shared__ float tile[32][33];
  int c0 = blockIdx.x * 32, r0 = blockIdx.y * 32;
  int tx = threadIdx.x, ty = threadIdx.y;
#pragma unroll
  for (int j = 0; j < 4; ++j) {
    int r = ty + j * 8;
    tile[r][tx] = in[(size_t)(r0 + r) * C + c0 + tx];
  }
  __syncthreads();
#pragma unroll
  for (int j = 0; j < 4; ++j) {
    int c = ty + j * 8;
    out[(size_t)(c0 + c) * R + r0 + tx] = f2bf(tile[tx][c]);
  }
}

// ---------------- V section of QKV -> Vt[b][h][d][t] ----------------
__global__ void transpose_v_kernel(const bf16_t* __restrict__ qkv, bf16_t* __restrict__ vt) {
  __shared__ bf16_t tile[32][33];
  int b = blockIdx.z;
  int hd0 = blockIdx.x * 32, t0 = blockIdx.y * 32;
  int tx = threadIdx.x, ty = threadIdx.y;
#pragma unroll
  for (int j = 0; j < 4; ++j) {
    int tt = ty + j * 8;
    tile[tt][tx] = qkv[(size_t)(b * T_ + t0 + tt) * NQKV + (E_ + NKV) + hd0 + tx];
  }
  __syncthreads();
#pragma unroll
  for (int j = 0; j < 4; ++j) {
    int hh = ty + j * 8;
    vt[(size_t)(b * NKV + hd0 + hh) * T_ + t0 + tx] = tile[tx][hh];
  }
}

// ================= 8-phase 256-wide GEMM: C = A[M,K] * BT[N,K]^T =================
// BM=256, BK=64, 512 thr = 8 waves (2M x 4N). Double-buffered LDS.
// Phase rhythm: {ds_read cur; stage next; BAR; MFMA; VMW(n); BAR} — the VMW sits
// BEFORE the closing barrier so every wave's own staging loads for the half-tile
// read in the NEXT phase are complete before any wave crosses; the barrier turns
// 8 per-wave guarantees into a block-wide one (round-5 bug: VMW after the
// barrier, i.e. at phase start, only covered the wave's own 8-row stripe).
// Counted vmcnt, never 0 in-loop. XOR swizzle slot^=row&7 (pre-swizzled global
// source + swizzled ds_reads, rule #21).
#define VMW(n) asm volatile("s_waitcnt vmcnt(" #n ")" ::: "memory")
#define BARSYNC do { asm volatile("" ::: "memory");            \
                     __builtin_amdgcn_s_barrier();             \
                     asm volatile("" ::: "memory"); } while (0)

template <int BN, int OUTMODE>
__global__ __launch_bounds__(512, 2)
void gemm8_kernel(const bf16_t* __restrict__ A, const bf16_t* __restrict__ BT,
                  void* __restrict__ Cv, const float* __restrict__ bias,
                  int M, int N, int K) {
  constexpr int BM = 256, BK = 64;
  constexpr int WN = BN / 4;               // wave cols: 64 or 32
  constexpr int ACN = (BN == 256) ? 4 : 2; // n-frags per wave
  __shared__ bf16_t As[2][BM * BK];
  __shared__ bf16_t Bs[2][BN * BK];

  const int tid = threadIdx.x;
  const int wid = tid >> 6, lane = tid & 63;
  const int l15 = lane & 15, l4 = lane >> 4;
  const int wr = wid >> 2, wc = wid & 3;
  const int m0 = blockIdx.x * BM, n0 = blockIdx.y * BN;
  const int srow = lane >> 3;                       // 0..7 within 8-row stripe
  const int schunk = (lane & 7) ^ srow;             // pre-swizzled source 16B-chunk

  f32x4 acc[8][ACN];
  f32x4 zero = {0.f, 0.f, 0.f, 0.f};
#pragma unroll
  for (int i = 0; i < 8; ++i)
#pragma unroll
    for (int j = 0; j < ACN; ++j) acc[i][j] = zero;

  // ---- staging: wave-uniform LDS base + per-lane pre-swizzled source ----
#define STAGE_A(nb, h, ktt) do {                                                        \
    int k0s = (ktt) * BK;                                                               \
    _Pragma("unroll") for (int j = 0; j < 2; ++j) {                                     \
      int row0 = (h) * 64 + j * 128 + wid * 8;                                          \
      __builtin_amdgcn_global_load_lds(                                                 \
          (glb_u32*)(A + (size_t)(m0 + row0 + srow) * K + k0s + schunk * 8),            \
          (lds_u32*)(&As[nb][row0 * 64]), 16, 0, 0);                                    \
    } } while (0)

#define STAGE_B2(nb, h, ktt) do {                                                       \
    int k0s = (ktt) * BK;                                                               \
    _Pragma("unroll") for (int j = 0; j < 2; ++j) {                                     \
      int i0 = j * 64 + wid * 8;                                                        \
      int row0 = (i0 & 31) + ((i0 >> 5) << 6) + (h) * 32;                               \
      __builtin_amdgcn_global_load_lds(                                                 \
          (glb_u32*)(BT + (size_t)(n0 + row0 + srow) * K + k0s + schunk * 8),           \
          (lds_u32*)(&Bs[nb][row0 * 64]), 16, 0, 0);                                    \
    } } while (0)

#define STAGE_B1(nb, ktt) do {                                                          \
    int k0s = (ktt) * BK;                                                               \
    _Pragma("unroll") for (int j = 0; j < 2; ++j) {                                     \
      int row0 = j * 64 + wid * 8;                                                      \
      __builtin_amdgcn_global_load_lds(                                                 \
          (glb_u32*)(BT + (size_t)(n0 + row0 + srow) * K + k0s + schunk * 8),           \
          (lds_u32*)(&Bs[nb][row0 * 64]), 16, 0, 0);                                    \
    } } while (0)

  // ---- fragment reads (swizzled): slot' = (ks*4+l4) ^ (row&7); row&7 == l15&7 ----
  bf16x8 afr[4][2], bfr[2][2];
#define LDA(mh) { _Pragma("unroll") for (int mf = 0; mf < 4; ++mf)                      \
    _Pragma("unroll") for (int ks = 0; ks < 2; ++ks) {                                  \
      int row = wr * 128 + (mh) * 64 + mf * 16 + l15;                                   \
      afr[mf][ks] = *(const bf16x8*)&As[cur][row * 64 + ((ks * 4 + l4) ^ (l15 & 7)) * 8]; } }

#define LDB(nh) { _Pragma("unroll") for (int nf = 0; nf < 2; ++nf)                      \
    _Pragma("unroll") for (int ks = 0; ks < 2; ++ks) {                                  \
      int row = wc * WN + (nh) * 32 + nf * 16 + l15;                                    \
      bfr[nf][ks] = *(const bf16x8*)&Bs[cur][row * 64 + ((ks * 4 + l4) ^ (l15 & 7)) * 8]; } }

#define MMA(mh, nh) {                                                                   \
    __builtin_amdgcn_s_setprio(1);                                                      \
    _Pragma("unroll") for (int ks = 0; ks < 2; ++ks)                                    \
      _Pragma("unroll") for (int mf = 0; mf < 4; ++mf)                                  \
        _Pragma("unroll") for (int nf = 0; nf < 2; ++nf)                                \
          acc[(mh) * 4 + mf][(nh) * 2 + nf] = __builtin_amdgcn_mfma_f32_16x16x32_bf16(  \
              afr[mf][ks], bfr[nf][ks], acc[(mh) * 4 + mf][(nh) * 2 + nf], 0, 0, 0);    \
    __builtin_amdgcn_s_setprio(0); }

  const int nK = K >> 6;

  // ---- prologue: stage tile 0 in ledger order, then wait halves for P0 ----
  if (BN == 256) {
    STAGE_A(0, 0, 0); STAGE_B2(0, 0, 0); STAGE_B2(0, 1, 0); STAGE_A(0, 1, 0);
    VMW(4);                       // A0,B0 of tile 0 landed (per wave)
  } else {
    STAGE_A(0, 0, 0); STAGE_B1(0, 0);    STAGE_A(0, 1, 0);
    VMW(2);                       // A0,B of tile 0 landed
  }
  BARSYNC;                        // block-wide: tile-0 halves visible

  for (int kt = 0; kt < nK; ++kt) {
    const int cur = kt & 1, nb = cur ^ 1;
    const int ktn = (kt + 1 < nK) ? kt + 1 : 0;   // dummy re-stage keeps ledger exact

    if (BN == 256) {
      // P0: read A0,B0(kt); stage A0(kt+1). End: complete B1(kt) for P1.
      LDA(0); LDB(0);
      STAGE_A(nb, 0, ktn);
      BARSYNC; MMA(0, 0); VMW(4); BARSYNC;
      // P1: read B1(kt); stage B0(kt+1). End: complete A1(kt) for P2.
      LDB(1);
      STAGE_B2(nb, 0, ktn);
      BARSYNC; MMA(0, 1); VMW(4); BARSYNC;
      // P2: read A1(kt); stage B1(kt+1). P3 re-reads B0(kt) (done) -> no wait.
      LDA(1);
      STAGE_B2(nb, 1, ktn);
      BARSYNC; MMA(1, 1); BARSYNC;
      // P3: re-read B0(kt); stage A1(kt+1). End: complete A0,B0(kt+1) for next P0.
      LDB(0);
      STAGE_A(nb, 1, ktn);
      BARSYNC; MMA(1, 0); VMW(4); BARSYNC;
    } else {
      // P0: read A0,B(kt); stage A0,B(kt+1). End: complete A1(kt) for P1.
      LDA(0); LDB(0);
      STAGE_A(nb, 0, ktn); STAGE_B1(nb, ktn);
      BARSYNC; MMA(0, 0); VMW(4); BARSYNC;
      // P1: read A1(kt) (B frags reused from regs); stage A1(kt+1).
      // End: complete A0,B(kt+1) for next P0.
      LDA(1);
      STAGE_A(nb, 1, ktn);
      BARSYNC; MMA(1, 0); VMW(2); BARSYNC;
    }
  }
  VMW(0);   // retire dummy stages before epilogue / endpgm

  // ---- epilogue ----
#pragma unroll
  for (int mq = 0; mq < 8; ++mq)
#pragma unroll
    for (int nq = 0; nq < ACN; ++nq) {
      int mrow = m0 + wr * 128 + (mq >> 2) * 64 + (mq & 3) * 16 + l4 * 4;
      int ncol = n0 + wc * WN + (nq >> 1) * 32 + (nq & 1) * 16 + l15;
      if (OUTMODE == 0) {
        bf16_t* C = reinterpret_cast<bf16_t*>(Cv);
#pragma unroll
        for (int r = 0; r < 4; ++r)
          C[(size_t)(mrow + r) * N + ncol] = f2bf(acc[mq][nq][r]);
      } else {
        float* C = reinterpret_cast<float*>(Cv);
        float bb = bias[ncol];
#pragma unroll
        for (int r = 0; r < 4; ++r)
          C[(size_t)(mrow + r) * N + ncol] = acc[mq][nq][r] + bb;
      }
    }
#undef STAGE_A
#undef STAGE_B2
#undef STAGE_B1
#undef LDA
#undef LDB
#undef MMA
}

// ---------------- flash attention (unchanged from round 4) ----------------
__global__ void attn_kernel(const bf16_t* __restrict__ qkv, const bf16_t* __restrict__ vt,
                            bf16_t* __restrict__ attn) {
  __shared__ bf16_t Kbuf[2][64 * 64];
  __shared__ bf16_t Vbuf[2][64 * 64];
  __shared__ float bcast[8][32];

  int tid = threadIdx.x;
  int w = tid >> 6, lane = tid & 63;
  int l31 = lane & 31, hi = lane >> 5;
  int bh = blockIdx.y;
  int b = bh >> 5, hq = bh & 31, hkv = hq >> 2;
  int q0 = blockIdx.x * 256 + w * 32;

  bf16x8 qf[4];
  {
    const bf16_t* qp = qkv + (size_t)(b * T_ + q0 + l31) * NQKV + hq * HD_;
#pragma unroll
    for (int s = 0; s < 4; ++s) {
      bf16x8 q = *reinterpret_cast<const bf16x8*>(qp + s * 16 + hi * 8);
#pragma unroll
      for (int e = 0; e < 8; ++e) q[e] = (bf16_t)((float)q[e] * SCALE_LOG2E);
      qf[s] = q;
    }
  }

  f32x16 o0 = {0.f,0.f,0.f,0.f,0.f,0.f,0.f,0.f,0.f,0.f,0.f,0.f,0.f,0.f,0.f,0.f};
  f32x16 o1 = o0;
  float m_r = -1e30f, l_r = 0.f;

  int srow = w * 8 + (lane >> 3);
  int schunk = (lane & 7) ^ ((lane >> 3) & 7);
  const bf16_t* kg = qkv + (size_t)b * T_ * NQKV + E_ + hkv * HD_;
  const bf16_t* vg = vt + ((size_t)(b * HKV_ + hkv) * HD_ + srow) * T_;

#define STAGE_KV(bi, kv0) do {                                                          \
    __builtin_amdgcn_global_load_lds(                                                   \
        (glb_u32*)(kg + (size_t)((kv0) + srow) * NQKV + schunk * 8),                    \
        (lds_u32*)(&Kbuf[bi][w * 8 * 64]), 16, 0, 0);                                   \
    __builtin_amdgcn_global_load_lds(                                                   \
        (glb_u32*)(vg + (kv0) + schunk * 8),                                            \
        (lds_u32*)(&Vbuf[bi][w * 8 * 64]), 16, 0, 0);                                   \
  } while (0)

#define KREAD(bi, tsub, s) \
  (*reinterpret_cast<const bf16x8*>(&Kbuf[bi][((tsub) * 32 + l31) * 64 + \
      ((((s) * 2 + hi) ^ (l31 & 7)) * 8)]))
#define VREAD(bi, dh, s) \
  (*reinterpret_cast<const bf16x8*>(&Vbuf[bi][((dh) * 32 + l31) * 64 + \
      ((((s) * 2 + hi) ^ (l31 & 7)) * 8)]))

  STAGE_KV(0, 0);
  __syncthreads();

#pragma unroll 2
  for (int t = 0; t < T_ / 64; ++t) {
    int bi = t & 1;
    if (t < T_ / 64 - 1) STAGE_KV(bi ^ 1, (t + 1) * 64);

    f32x16 sa = {0.f,0.f,0.f,0.f,0.f,0.f,0.f,0.f,0.f,0.f,0.f,0.f,0.f,0.f,0.f,0.f};
    f32x16 sb = sa;
    __builtin_amdgcn_s_setprio(1);
#pragma unroll
    for (int s = 0; s < 4; ++s) {
      sa = __builtin_amdgcn_mfma_f32_32x32x16_bf16(KREAD(bi, 0, s), qf[s], sa, 0, 0, 0);
      sb = __builtin_amdgcn_mfma_f32_32x32x16_bf16(KREAD(bi, 1, s), qf[s], sb, 0, 0, 0);
    }
    __builtin_amdgcn_s_setprio(0);

    float pmax = sa[0];
#pragma unroll
    for (int r = 1; r < 16; ++r) pmax = fmaxf(pmax, sa[r]);
#pragma unroll
    for (int r = 0; r < 16; ++r) pmax = fmaxf(pmax, sb[r]);

    if (__any(pmax > m_r + 8.f)) {
      float pm2 = __shfl_xor(pmax, 32);
      float mnew = fmaxf(m_r, fmaxf(pmax, pm2));
      float corr = fexp2(m_r - mnew);
      m_r = mnew;
      l_r *= corr;
      bcast[w][l31] = corr;
      asm volatile("s_waitcnt lgkmcnt(0)" ::: "memory");
#pragma unroll
      for (int r = 0; r < 16; ++r) {
        float c = bcast[w][(r & 3) + 8 * (r >> 2) + 4 * hi];
        o0[r] *= c; o1[r] *= c;
      }
    }

    float pA[16], pB[16];
    float ps0 = 0.f, ps1 = 0.f;
#pragma unroll
    for (int r = 0; r < 16; ++r) {
      pA[r] = fexp2(sa[r] - m_r); ps0 += pA[r];
      pB[r] = fexp2(sb[r] - m_r); ps1 += pB[r];
    }
    l_r += ps0 + ps1;

    unsigned wd[2][4][2];
#pragma unroll
    for (int g = 0; g < 4; ++g)
#pragma unroll
      for (int j = 0; j < 2; ++j) {
        wd[0][g][j] = pack2bf(pA[4 * g + 2 * j], pA[4 * g + 2 * j + 1]);
        wd[1][g][j] = pack2bf(pB[4 * g + 2 * j], pB[4 * g + 2 * j + 1]);
      }

    __builtin_amdgcn_s_setprio(1);
#pragma unroll
    for (int s = 0; s < 4; ++s) {
      const int tt = s >> 1, gg = 2 * (s & 1);
      unsigned send0 = hi ? wd[tt][gg][0] : wd[tt][gg + 1][0];
      unsigned send1 = hi ? wd[tt][gg][1] : wd[tt][gg + 1][1];
      unsigned recv0 = __shfl_xor(send0, 32);
      unsigned recv1 = __shfl_xor(send1, 32);
      union { unsigned u[4]; bf16x8 v; } pf;
      pf.u[0] = hi ? recv0 : wd[tt][gg][0];
      pf.u[1] = hi ? recv1 : wd[tt][gg][1];
      pf.u[2] = hi ? wd[tt][gg + 1][0] : recv0;
      pf.u[3] = hi ? wd[tt][gg + 1][1] : recv1;
      o0 = __builtin_amdgcn_mfma_f32_32x32x16_bf16(pf.v, VREAD(bi, 0, s), o0, 0, 0, 0);
      o1 = __builtin_amdgcn_mfma_f32_32x32x16_bf16(pf.v, VREAD(bi, 1, s), o1, 0, 0, 0);
    }
    __builtin_amdgcn_s_setprio(0);

    __syncthreads();
  }
#undef STAGE_KV
#undef KREAD
#undef VREAD

  float lfull = l_r + __shfl_xor(l_r, 32);
  bcast[w][l31] = 1.0f / lfull;
  asm volatile("s_waitcnt lgkmcnt(0)" ::: "memory");
  const size_t obase = (size_t)(b * T_ + q0) * E_ + hq * HD_;
#pragma unroll
  for (int r = 0; r < 16; ++r) {
    int q = (r & 3) + 8 * (r >> 2) + 4 * hi;
    float rl = bcast[w][q];
    attn[obase + (size_t)q * E_ + l31]      = (bf16_t)(o0[r] * rl);
    attn[obase + (size_t)q * E_ + 32 + l31] = (bf16_t)(o1[r] * rl);
  }
}

extern "C" void kernel_launch(void* const* d_in, const int* in_sizes, int n_in,
                              void* d_out, int out_size, void* d_ws, size_t ws_size,
                              hipStream_t stream) {
  const float* x  = (const float*)d_in[0];
  const float* Wq = (const float*)d_in[1];
  const float* Wk = (const float*)d_in[2];
  const float* Wv = (const float*)d_in[3];
  const float* Wo = (const float*)d_in[4];
  const float* bo = (const float*)d_in[5];
  float* out = (float*)d_out;

  bf16_t* xb    = (bf16_t*)d_ws;                         // 4096*2048
  bf16_t* WcatT = xb + (size_t)MROWS * E_;               // 3072*2048
  bf16_t* WoT   = WcatT + (size_t)NQKV * E_;             // 2048*2048
  bf16_t* QKV   = WoT + (size_t)E_ * E_;                 // 4096*3072
  bf16_t* Vt    = QKV + (size_t)MROWS * NQKV;            // 2*512*2048
  bf16_t* Attn  = Vt + (size_t)B_ * NKV * T_;            // 4096*2048

  dim3 tblk(32, 8);
  cast_x_kernel<<<2048, 256, 0, stream>>>(x, xb, MROWS * E_ / 8);
  transpose_cast_w<<<dim3(E_ / 32, E_ / 32), tblk, 0, stream>>>(Wq, WcatT, E_, E_);
  transpose_cast_w<<<dim3(NKV / 32, E_ / 32), tblk, 0, stream>>>(Wk, WcatT + (size_t)E_ * E_, E_, NKV);
  transpose_cast_w<<<dim3(NKV / 32, E_ / 32), tblk, 0, stream>>>(Wv, WcatT + (size_t)(E_ + NKV) * E_, E_, NKV);
  transpose_cast_w<<<dim3(E_ / 32, E_ / 32), tblk, 0, stream>>>(Wo, WoT, E_, E_);

  gemm8_kernel<256, 0><<<dim3(MROWS / 256, NQKV / 256), 512, 0, stream>>>(
      xb, WcatT, (void*)QKV, nullptr, MROWS, NQKV, E_);

  transpose_v_kernel<<<dim3(NKV / 32, T_ / 32, B_), tblk, 0, stream>>>(QKV, Vt);

  attn_kernel<<<dim3(T_ / 256, B_ * HQ_), 512, 0, stream>>>(QKV, Vt, Attn);

  gemm8_kernel<128, 1><<<dim3(MROWS / 256, E_ / 128), 512, 0, stream>>>(
      Attn, WoT, (void*)out, bo, MROWS, E_, E_);
}